// Round 8
// baseline (348.304 us; speedup 1.0000x reference)
//
#include <hip/hip_runtime.h>

typedef __attribute__((ext_vector_type(4))) float f32x4;
typedef __attribute__((ext_vector_type(4))) short s16x4;
typedef __attribute__((ext_vector_type(8))) short s16x8;

constexpr int Bn = 2, Hn = 16, Sn = 2048, DHn = 64;
constexpr int TQ = 64;              // q rows per block (2 q-groups x 32)
constexpr int TK = 64;              // keys per tile
constexpr int NT = Sn / TK;         // 32 tiles total; 16 per key-half
constexpr int TILE_SH = TK * DHn;   // 4096 shorts (8 KB) per packed tile
constexpr float SHIFT = 16.0f;      // fixed softmax shift (|scores*log2e| < ~9)

// pack two floats to bf16x2 (round-to-nearest-even), low = a, high = b
__device__ __forceinline__ unsigned pk2(float a, float b) {
  unsigned ua = __builtin_bit_cast(unsigned, a);
  unsigned ub = __builtin_bit_cast(unsigned, b);
  ua += 0x7fffu + ((ua >> 16) & 1u);
  ub += 0x7fffu + ((ub >> 16) & 1u);
  return (ua >> 16) | (ub & 0xffff0000u);
}

// hot-path pack: single-instruction v_cvt_pk_bf16_f32 when available
__device__ __forceinline__ unsigned pkP(float a, float b) {
#if __has_builtin(__builtin_amdgcn_cvt_pk_bf16_f32)
  auto r = __builtin_amdgcn_cvt_pk_bf16_f32(a, b);
  unsigned u;
  __builtin_memcpy(&u, &r, 4);
  return u;
#else
  return pk2(a, b);
#endif
}

__device__ __forceinline__ float fexp2(float x) {
#if __has_builtin(__builtin_amdgcn_exp2f)
  return __builtin_amdgcn_exp2f(x);
#else
  return exp2f(x);
#endif
}

// ---------------- prepass: K/V -> bf16 swizzled fragment-native tiles + bias table ----
// Tile (bh,t) contiguous 4096 shorts:
//   Kp: row r(key), 16B chunk c (=d>>3) stored at chunk c^(r&7)
//   Vp: row d,      16B chunk c (=key>>3) stored at chunk c^(d&7)
__global__ __launch_bounds__(256, 4)
void prepack_kernel(const float* __restrict__ Kg, const float* __restrict__ Vg,
                    const unsigned char* __restrict__ maskg,
                    short* __restrict__ Kp, short* __restrict__ Vp,
                    float* __restrict__ biasg) {
  const int blk = blockIdx.x;
  const int tid = threadIdx.x;
  const float* Kt = Kg + (size_t)blk * TILE_SH;
  const float* Vt = Vg + (size_t)blk * TILE_SH;
  short* Kd = Kp + (size_t)blk * TILE_SH;
  short* Vd = Vp + (size_t)blk * TILE_SH;

  // K: thread -> row r = tid>>2, two 16B chunks
  {
    const int r = tid >> 2;
    const int cb = (tid & 3) * 2;
#pragma unroll
    for (int cc = 0; cc < 2; ++cc) {
      int c = cb + cc;
      const float4* p = (const float4*)(Kt + (size_t)r * DHn + c * 8);
      float4 x = p[0], y = p[1];
      union { unsigned u[4]; s16x8 v; } tmp;
      tmp.u[0] = pk2(x.x, x.y); tmp.u[1] = pk2(x.z, x.w);
      tmp.u[2] = pk2(y.x, y.y); tmp.u[3] = pk2(y.z, y.w);
      *(s16x8*)&Kd[r * 64 + (c ^ (r & 7)) * 8] = tmp.v;
    }
  }
  // V^T via 4x4 in-register transpose: thread owns keys k0..k0+3 x dims d0..d0+3
  {
    const int tx = tid & 15, ty = tid >> 4;
    const int d0 = tx * 4, k0 = ty * 4;
    float4 r_[4];
#pragma unroll
    for (int i = 0; i < 4; ++i)
      r_[i] = *(const float4*)(Vt + (size_t)(k0 + i) * DHn + d0);
    float c_[4][4] = {
        {r_[0].x, r_[1].x, r_[2].x, r_[3].x},
        {r_[0].y, r_[1].y, r_[2].y, r_[3].y},
        {r_[0].z, r_[1].z, r_[2].z, r_[3].z},
        {r_[0].w, r_[1].w, r_[2].w, r_[3].w}};
    const int c = k0 >> 3;
#pragma unroll
    for (int j = 0; j < 4; ++j) {
      int d = d0 + j;
      union { unsigned u[2]; s16x4 v4; } st;
      st.u[0] = pk2(c_[j][0], c_[j][1]);
      st.u[1] = pk2(c_[j][2], c_[j][3]);
      *(s16x4*)&Vd[d * 64 + ((c ^ (d & 7)) * 8) + (k0 & 7)] = st.v4;
    }
  }
  if (tid < TK) {
    const int bh = blk >> 5, t = blk & 31, b = bh >> 4;
    biasg[b * Sn + t * TK + tid] = maskg[b * Sn + t * TK + tid] ? -1e30f : -SHIFT;
  }
}

// ---------------- main kernel: 256 thr / 4 waves; in-block split-K x2 ----------------
// wave w: kh = w>>1 (key half, 16 tiles), wq = w&1 (q group of 32 rows)
__global__ __launch_bounds__(256, 4)
void fattn_kernel(const float* __restrict__ Qg, const short* __restrict__ Kp,
                  const short* __restrict__ Vp, const float* __restrict__ biasg,
                  float* __restrict__ Og) {
  __shared__ __align__(16) short Psh[4 * 32 * 64];   // 16 KB: per-wave P rows, swizzled
  __shared__ __align__(16) float Xch[2 * 64 * 41];   // 20.5 KB: split-K exchange, pad 41

  const int tid  = threadIdx.x;
  const int w    = tid >> 6;
  const int lane = tid & 63;
  const int n    = lane & 15;
  const int q4   = lane >> 4;
  const int swz  = n & 7;
  const int kh   = w >> 1;
  const int wq   = w & 1;

  const int blk = blockIdx.x;
  const int bh  = blk & 31;          // bh-major: co-resident blocks share bh -> L2-hot tiles
  const int qt  = blk >> 5;
  const int b   = bh >> 4;
  const int h   = bh & 15;

  const float* Qb  = Qg + (size_t)bh * Sn * DHn;
  const short* Kt0 = Kp + (size_t)bh * NT * TILE_SH;
  const short* Vt0 = Vp + (size_t)bh * NT * TILE_SH;
  const float* bq0 = biasg + (size_t)b * Sn;

  const int q0 = qt * TQ + wq * 32;

  // ---- Q B-fragments for both 16-col groups, scale*log2(e) folded ----
  const float c1 = 0.125f * 1.4426950408889634f;
  s16x8 qf[2][2];
#pragma unroll
  for (int qg = 0; qg < 2; ++qg) {
    const float* qrow = Qb + (size_t)(q0 + qg * 16 + n) * DHn;
#pragma unroll
    for (int kc = 0; kc < 2; ++kc) {
      const float4* p = (const float4*)(qrow + kc * 32 + q4 * 8);
      float4 x = p[0], y = p[1];
      union { unsigned u[4]; s16x8 v; } tmp;
      tmp.u[0] = pk2(x.x * c1, x.y * c1);
      tmp.u[1] = pk2(x.z * c1, x.w * c1);
      tmp.u[2] = pk2(y.x * c1, y.y * c1);
      tmp.u[3] = pk2(y.z * c1, y.w * c1);
      qf[qg][kc] = tmp.v;
    }
  }

  // ---- tile-invariant fragment offsets (shorts, within a packed tile) ----
  const int c0    = q4 ^ swz;
  const int offA  = n * 64 + c0 * 8;        // kc=0 (rows 16mc+n via +1024*mc)
  const int offB  = n * 64 + (c0 ^ 4) * 8;  // kc=1
  const int prowA = (w * 32 + n) * 64;      // P row base (qg adds 16*64)
  const int pc    = (q4 >> 1) ^ swz;        // P-write chunk base, ^(2mc) per mc
  const int pwo   = (q4 & 1) * 4;

  // all-ones bf16 B-fragment for MFMA row-sum
  s16x8 ones;
#pragma unroll
  for (int i = 0; i < 8; ++i) ones[i] = (short)0x3F80;

  f32x4 Oa[2][4];
#pragma unroll
  for (int qg = 0; qg < 2; ++qg)
#pragma unroll
    for (int na = 0; na < 4; ++na) Oa[qg][na] = (f32x4){0.f, 0.f, 0.f, 0.f};
  f32x4 lacc[2] = {(f32x4){0.f, 0.f, 0.f, 0.f}, (f32x4){0.f, 0.f, 0.f, 0.f}};

  auto load_tile = [&](s16x8 kf[4][2], s16x8 vf[4][2], int t) {
    const short* Ka = Kt0 + (size_t)t * TILE_SH;
    const short* Va = Vt0 + (size_t)t * TILE_SH;
#pragma unroll
    for (int mc = 0; mc < 4; ++mc) {
      kf[mc][0] = *(const s16x8*)&Ka[mc * 1024 + offA];
      kf[mc][1] = *(const s16x8*)&Ka[mc * 1024 + offB];
      vf[mc][0] = *(const s16x8*)&Va[mc * 1024 + offA];
      vf[mc][1] = *(const s16x8*)&Va[mc * 1024 + offB];
    }
  };

  auto compute_tile = [&](s16x8 kf[4][2], s16x8 vf[4][2], int t) {
    f32x4 bias[4];
    {
      const float* bq = bq0 + t * TK + q4 * 4;
#pragma unroll
      for (int mc = 0; mc < 4; ++mc) bias[mc] = *(const f32x4*)(bq + mc * 16);
    }
#pragma unroll
    for (int qg = 0; qg < 2; ++qg) {
      f32x4 sa[4];
#pragma unroll
      for (int mc = 0; mc < 4; ++mc) sa[mc] = bias[mc];
#pragma unroll
      for (int mc = 0; mc < 4; ++mc)
#pragma unroll
        for (int kc = 0; kc < 2; ++kc)
          sa[mc] = __builtin_amdgcn_mfma_f32_16x16x32_bf16(kf[mc][kc], qf[qg][kc], sa[mc], 0, 0, 0);

      const int prow = prowA + qg * (16 * 64);
#pragma unroll
      for (int mc = 0; mc < 4; ++mc) {
        float p0 = fexp2(sa[mc][0]);
        float p1 = fexp2(sa[mc][1]);
        float p2 = fexp2(sa[mc][2]);
        float p3 = fexp2(sa[mc][3]);
        union { unsigned u[2]; s16x4 v4; } pw;
        pw.u[0] = pkP(p0, p1);
        pw.u[1] = pkP(p2, p3);
        *(s16x4*)&Psh[prow + ((pc ^ (2 * mc)) * 8) + pwo] = pw.v4;
      }
    }
#pragma unroll
    for (int qg = 0; qg < 2; ++qg) {
      const int prow = prowA + qg * (16 * 64);
      s16x8 pf[2];
      pf[0] = *(const s16x8*)&Psh[prow + ((q4 ^ swz) * 8)];
      pf[1] = *(const s16x8*)&Psh[prow + (((4 + q4) ^ swz) * 8)];
      lacc[qg] = __builtin_amdgcn_mfma_f32_16x16x32_bf16(pf[0], ones, lacc[qg], 0, 0, 0);
      lacc[qg] = __builtin_amdgcn_mfma_f32_16x16x32_bf16(pf[1], ones, lacc[qg], 0, 0, 0);
#pragma unroll
      for (int na = 0; na < 4; ++na)
#pragma unroll
        for (int kc = 0; kc < 2; ++kc)
          Oa[qg][na] = __builtin_amdgcn_mfma_f32_16x16x32_bf16(pf[kc], vf[na][kc], Oa[qg][na], 0, 0, 0);
    }
  };

  // ---- ping-pong over this wave's 16 tiles; no barriers in the loop ----
  const int t0 = kh * 16;
  s16x8 kfA[4][2], vfA[4][2], kfB[4][2], vfB[4][2];
  load_tile(kfA, vfA, t0);
  for (int tt = 0; tt < 16; tt += 2) {
    load_tile(kfB, vfB, t0 + tt + 1);
    compute_tile(kfA, vfA, t0 + tt);
    if (tt + 2 < 16) load_tile(kfA, vfA, t0 + tt + 2);
    compute_tile(kfB, vfB, t0 + tt + 1);
  }

  // ---- split-K combine: kh=1 waves publish unnormalized partials via LDS ----
  __syncthreads();  // all waves done with Psh & their tiles
  const int xbase = (wq * 64 + lane) * 41;
  if (kh == 1) {
#pragma unroll
    for (int qg = 0; qg < 2; ++qg) {
#pragma unroll
      for (int na = 0; na < 4; ++na)
#pragma unroll
        for (int r = 0; r < 4; ++r)
          Xch[xbase + qg * 16 + na * 4 + r] = Oa[qg][na][r];
#pragma unroll
      for (int r = 0; r < 4; ++r)
        Xch[xbase + 32 + qg * 4 + r] = lacc[qg][r];
    }
  }
  __syncthreads();
  if (kh == 0) {
#pragma unroll
    for (int qg = 0; qg < 2; ++qg) {
#pragma unroll
      for (int r = 0; r < 4; ++r) {
        float l = lacc[qg][r] + Xch[xbase + 32 + qg * 4 + r];
        float inv = 1.0f / l;
        int q = q0 + qg * 16 + q4 * 4 + r;
        float* orow = Og + (size_t)(b * Sn + q) * (Hn * DHn) + h * DHn;
#pragma unroll
        for (int na = 0; na < 4; ++na)
          orow[na * 16 + n] = (Oa[qg][na][r] + Xch[xbase + qg * 16 + na * 4 + r]) * inv;
      }
    }
  }
}

extern "C" void kernel_launch(void* const* d_in, const int* in_sizes, int n_in,
                              void* d_out, int out_size, void* d_ws, size_t ws_size,
                              hipStream_t stream) {
  (void)in_sizes; (void)n_in; (void)ws_size; (void)out_size;
  const float* Q = (const float*)d_in[0];
  const float* K = (const float*)d_in[1];
  const float* V = (const float*)d_in[2];
  const unsigned char* mask = (const unsigned char*)d_in[3];
  float* out = (float*)d_out;

  short* Kp = (short*)d_ws;                                  // 8 MB
  short* Vp = Kp + (size_t)Bn * Hn * Sn * DHn;               // 8 MB
  float* biasg = (float*)(Vp + (size_t)Bn * Hn * Sn * DHn);  // 16 KB

  hipLaunchKernelGGL(prepack_kernel, dim3(Bn * Hn * NT), dim3(256), 0, stream,
                     K, V, mask, Kp, Vp, biasg);
  hipLaunchKernelGGL(fattn_kernel, dim3(Bn * Hn * (Sn / TQ)), dim3(256), 0, stream,
                     Q, Kp, Vp, biasg, out);
}

// Round 9
// 197.817 us; speedup vs baseline: 1.7607x; 1.7607x over previous
//
#include <hip/hip_runtime.h>

typedef __attribute__((ext_vector_type(4))) float f32x4;
typedef __attribute__((ext_vector_type(4))) short s16x4;
typedef __attribute__((ext_vector_type(8))) short s16x8;

constexpr int Bn = 2, Hn = 16, Sn = 2048, DHn = 64;
constexpr int TQ = 64;              // q rows per block (2 q-groups x 32)
constexpr int TK = 64;              // keys per tile
constexpr int NT = Sn / TK;         // 32 tiles total; 16 per key-half
constexpr int TILE_SH = TK * DHn;   // 4096 shorts (8 KB) per packed tile
constexpr float SHIFT = 16.0f;      // fixed softmax shift (|scores*log2e| < ~9)

// pack two floats to bf16x2 (round-to-nearest-even), low = a, high = b
__device__ __forceinline__ unsigned pk2(float a, float b) {
  unsigned ua = __builtin_bit_cast(unsigned, a);
  unsigned ub = __builtin_bit_cast(unsigned, b);
  ua += 0x7fffu + ((ua >> 16) & 1u);
  ub += 0x7fffu + ((ub >> 16) & 1u);
  return (ua >> 16) | (ub & 0xffff0000u);
}

// hot-path pack: single-instruction v_cvt_pk_bf16_f32 when available
__device__ __forceinline__ unsigned pkP(float a, float b) {
#if __has_builtin(__builtin_amdgcn_cvt_pk_bf16_f32)
  auto r = __builtin_amdgcn_cvt_pk_bf16_f32(a, b);
  unsigned u;
  __builtin_memcpy(&u, &r, 4);
  return u;
#else
  return pk2(a, b);
#endif
}

__device__ __forceinline__ float fexp2(float x) {
#if __has_builtin(__builtin_amdgcn_exp2f)
  return __builtin_amdgcn_exp2f(x);
#else
  return exp2f(x);
#endif
}

__device__ __forceinline__ void sched_fence() {
#if __has_builtin(__builtin_amdgcn_sched_barrier)
  __builtin_amdgcn_sched_barrier(0);
#endif
}

// ---------------- prepass: K/V -> bf16 swizzled fragment-native tiles + bias table ----
__global__ __launch_bounds__(256, 4)
void prepack_kernel(const float* __restrict__ Kg, const float* __restrict__ Vg,
                    const unsigned char* __restrict__ maskg,
                    short* __restrict__ Kp, short* __restrict__ Vp,
                    float* __restrict__ biasg) {
  const int blk = blockIdx.x;
  const int tid = threadIdx.x;
  const float* Kt = Kg + (size_t)blk * TILE_SH;
  const float* Vt = Vg + (size_t)blk * TILE_SH;
  short* Kd = Kp + (size_t)blk * TILE_SH;
  short* Vd = Vp + (size_t)blk * TILE_SH;

  // K: row r(key), 16B chunk c (=d>>3) stored at chunk c^(r&7)
  {
    const int r = tid >> 2;
    const int cb = (tid & 3) * 2;
#pragma unroll
    for (int cc = 0; cc < 2; ++cc) {
      int c = cb + cc;
      const float4* p = (const float4*)(Kt + (size_t)r * DHn + c * 8);
      float4 x = p[0], y = p[1];
      union { unsigned u[4]; s16x8 v; } tmp;
      tmp.u[0] = pk2(x.x, x.y); tmp.u[1] = pk2(x.z, x.w);
      tmp.u[2] = pk2(y.x, y.y); tmp.u[3] = pk2(y.z, y.w);
      *(s16x8*)&Kd[r * 64 + (c ^ (r & 7)) * 8] = tmp.v;
    }
  }
  // V^T via 4x4 in-register transpose; row d, chunk c (=key>>3) at c^(d&7)
  {
    const int tx = tid & 15, ty = tid >> 4;
    const int d0 = tx * 4, k0 = ty * 4;
    float4 r_[4];
#pragma unroll
    for (int i = 0; i < 4; ++i)
      r_[i] = *(const float4*)(Vt + (size_t)(k0 + i) * DHn + d0);
    float c_[4][4] = {
        {r_[0].x, r_[1].x, r_[2].x, r_[3].x},
        {r_[0].y, r_[1].y, r_[2].y, r_[3].y},
        {r_[0].z, r_[1].z, r_[2].z, r_[3].z},
        {r_[0].w, r_[1].w, r_[2].w, r_[3].w}};
    const int c = k0 >> 3;
#pragma unroll
    for (int j = 0; j < 4; ++j) {
      int d = d0 + j;
      union { unsigned u[2]; s16x4 v4; } st;
      st.u[0] = pk2(c_[j][0], c_[j][1]);
      st.u[1] = pk2(c_[j][2], c_[j][3]);
      *(s16x4*)&Vd[d * 64 + ((c ^ (d & 7)) * 8) + (k0 & 7)] = st.v4;
    }
  }
  if (tid < TK) {
    const int bh = blk >> 5, t = blk & 31, b = bh >> 4;
    biasg[b * Sn + t * TK + tid] = maskg[b * Sn + t * TK + tid] ? -1e30f : -SHIFT;
  }
}

// ---------------- main kernel: 256 thr / 4 waves; in-block split-K x2, low-VGPR ----
// wave w: kh = w>>1 (key half, 16 tiles), wq = w&1 (q group of 32 rows)
__global__ __launch_bounds__(256, 4)
void fattn_kernel(const float* __restrict__ Qg, const short* __restrict__ Kp,
                  const short* __restrict__ Vp, const float* __restrict__ biasg,
                  float* __restrict__ Og) {
  __shared__ __align__(16) short Psh[4 * 32 * 64];   // 16 KB: per-wave P rows, swizzled
  __shared__ __align__(16) float Xch[2 * 64 * 41];   // 20.5 KB: split-K exchange, stride 41

  const int tid  = threadIdx.x;
  const int w    = tid >> 6;
  const int lane = tid & 63;
  const int n    = lane & 15;
  const int q4   = lane >> 4;
  const int swz  = n & 7;
  const int kh   = w >> 1;
  const int wq   = w & 1;

  const int blk = blockIdx.x;
  const int bh  = blk & 31;          // bh-major: co-resident blocks share bh -> L2-hot tiles
  const int qt  = blk >> 5;
  const int b   = bh >> 4;
  const int h   = bh & 15;

  const float* Qb  = Qg + (size_t)bh * Sn * DHn;
  const short* Kt0 = Kp + (size_t)bh * NT * TILE_SH;
  const short* Vt0 = Vp + (size_t)bh * NT * TILE_SH;
  const float* bq0 = biasg + (size_t)b * Sn;

  const int q0 = qt * TQ + wq * 32;

  // ---- Q B-fragments for both 16-col groups, scale*log2(e) folded ----
  const float c1 = 0.125f * 1.4426950408889634f;
  s16x8 qf[2][2];
#pragma unroll
  for (int qg = 0; qg < 2; ++qg) {
    const float* qrow = Qb + (size_t)(q0 + qg * 16 + n) * DHn;
#pragma unroll
    for (int kc = 0; kc < 2; ++kc) {
      const float4* p = (const float4*)(qrow + kc * 32 + q4 * 8);
      float4 x = p[0], y = p[1];
      union { unsigned u[4]; s16x8 v; } tmp;
      tmp.u[0] = pk2(x.x * c1, x.y * c1);
      tmp.u[1] = pk2(x.z * c1, x.w * c1);
      tmp.u[2] = pk2(y.x * c1, y.y * c1);
      tmp.u[3] = pk2(y.z * c1, y.w * c1);
      qf[qg][kc] = tmp.v;
    }
  }

  // ---- tile-invariant fragment offsets (shorts, within a packed tile) ----
  const int c0    = q4 ^ swz;
  const int offA  = n * 64 + c0 * 8;        // kc=0 (rows 16mc+n via +1024*mc)
  const int offB  = n * 64 + (c0 ^ 4) * 8;  // kc=1
  const int prowA = (w * 32 + n) * 64;      // P row base (qg adds 16*64)
  const int pc    = (q4 >> 1) ^ swz;        // P-write chunk base, ^(2mc) per mc
  const int pwo   = (q4 & 1) * 4;

  f32x4 Oa[2][4];
#pragma unroll
  for (int qg = 0; qg < 2; ++qg)
#pragma unroll
    for (int na = 0; na < 4; ++na) Oa[qg][na] = (f32x4){0.f, 0.f, 0.f, 0.f};
  float lsum[2] = {0.f, 0.f};   // per-lane partial; cross-quad reduce deferred to epilogue

  const int t0 = kh * 16;
  for (int tt = 0; tt < 16; ++tt) {
    const int t = t0 + tt;
    const short* Ka = Kt0 + (size_t)t * TILE_SH;
    const short* Va = Vt0 + (size_t)t * TILE_SH;
    const float* bq = bq0 + t * TK + q4 * 4;

    // ---- phase 1: K fragments + QK MFMA + softmax + P write ----
    s16x8 kf[4][2];
#pragma unroll
    for (int mc = 0; mc < 4; ++mc) {
      kf[mc][0] = *(const s16x8*)&Ka[mc * 1024 + offA];
      kf[mc][1] = *(const s16x8*)&Ka[mc * 1024 + offB];
    }
#pragma unroll
    for (int qg = 0; qg < 2; ++qg) {
      f32x4 sa[4];
#pragma unroll
      for (int mc = 0; mc < 4; ++mc) sa[mc] = (f32x4){0.f, 0.f, 0.f, 0.f};
#pragma unroll
      for (int mc = 0; mc < 4; ++mc)
#pragma unroll
        for (int kc = 0; kc < 2; ++kc)
          sa[mc] = __builtin_amdgcn_mfma_f32_16x16x32_bf16(kf[mc][kc], qf[qg][kc], sa[mc], 0, 0, 0);

      const int prow = prowA + qg * (16 * 64);
      float ls = 0.f;
#pragma unroll
      for (int mc = 0; mc < 4; ++mc) {
        f32x4 bias = *(const f32x4*)(bq + mc * 16);
        float p0 = fexp2(sa[mc][0] + bias[0]);
        float p1 = fexp2(sa[mc][1] + bias[1]);
        float p2 = fexp2(sa[mc][2] + bias[2]);
        float p3 = fexp2(sa[mc][3] + bias[3]);
        ls += (p0 + p1) + (p2 + p3);
        union { unsigned u[2]; s16x4 v4; } pw;
        pw.u[0] = pkP(p0, p1);
        pw.u[1] = pkP(p2, p3);
        *(s16x4*)&Psh[prow + ((pc ^ (2 * mc)) * 8) + pwo] = pw.v4;
      }
      lsum[qg] += ls;
    }
    sched_fence();  // keep vf loads out of phase 1 (register-pressure fence)

    // ---- phase 2: V fragments + PV MFMA ----
    s16x8 vf[4][2];
#pragma unroll
    for (int na = 0; na < 4; ++na) {
      vf[na][0] = *(const s16x8*)&Va[na * 1024 + offA];
      vf[na][1] = *(const s16x8*)&Va[na * 1024 + offB];
    }
#pragma unroll
    for (int qg = 0; qg < 2; ++qg) {
      const int prow = prowA + qg * (16 * 64);
      s16x8 pf[2];
      pf[0] = *(const s16x8*)&Psh[prow + ((q4 ^ swz) * 8)];
      pf[1] = *(const s16x8*)&Psh[prow + (((4 + q4) ^ swz) * 8)];
#pragma unroll
      for (int na = 0; na < 4; ++na)
#pragma unroll
        for (int kc = 0; kc < 2; ++kc)
          Oa[qg][na] = __builtin_amdgcn_mfma_f32_16x16x32_bf16(pf[kc], vf[na][kc], Oa[qg][na], 0, 0, 0);
    }
    sched_fence();  // keep next tile's kf loads out of phase 2
  }

  // ---- split-K combine: kh=1 publishes unnormalized partials via LDS ----
  __syncthreads();
  const int xbase = (wq * 64 + lane) * 41;
  if (kh == 1) {
#pragma unroll
    for (int qg = 0; qg < 2; ++qg) {
#pragma unroll
      for (int na = 0; na < 4; ++na)
#pragma unroll
        for (int r = 0; r < 4; ++r)
          Xch[xbase + qg * 16 + na * 4 + r] = Oa[qg][na][r];
      Xch[xbase + 32 + qg] = lsum[qg];
    }
  }
  __syncthreads();
  if (kh == 0) {
#pragma unroll
    for (int qg = 0; qg < 2; ++qg) {
      float lq = lsum[qg] + Xch[xbase + 32 + qg];  // per-lane partial, both halves
      lq += __shfl_xor(lq, 16);
      lq += __shfl_xor(lq, 32);                    // lane n holds full row-sum for q=n
#pragma unroll
      for (int r = 0; r < 4; ++r) {
        float inv = 1.0f / __shfl(lq, q4 * 4 + r);
        int q = q0 + qg * 16 + q4 * 4 + r;
        float* orow = Og + (size_t)(b * Sn + q) * (Hn * DHn) + h * DHn;
#pragma unroll
        for (int na = 0; na < 4; ++na)
          orow[na * 16 + n] = (Oa[qg][na][r] + Xch[xbase + qg * 16 + na * 4 + r]) * inv;
      }
    }
  }
}

extern "C" void kernel_launch(void* const* d_in, const int* in_sizes, int n_in,
                              void* d_out, int out_size, void* d_ws, size_t ws_size,
                              hipStream_t stream) {
  (void)in_sizes; (void)n_in; (void)ws_size; (void)out_size;
  const float* Q = (const float*)d_in[0];
  const float* K = (const float*)d_in[1];
  const float* V = (const float*)d_in[2];
  const unsigned char* mask = (const unsigned char*)d_in[3];
  float* out = (float*)d_out;

  short* Kp = (short*)d_ws;                                  // 8 MB
  short* Vp = Kp + (size_t)Bn * Hn * Sn * DHn;               // 8 MB
  float* biasg = (float*)(Vp + (size_t)Bn * Hn * Sn * DHn);  // 16 KB

  hipLaunchKernelGGL(prepack_kernel, dim3(Bn * Hn * NT), dim3(256), 0, stream,
                     K, V, mask, Kp, Vp, biasg);
  hipLaunchKernelGGL(fattn_kernel, dim3(Bn * Hn * (Sn / TQ)), dim3(256), 0, stream,
                     Q, Kp, Vp, biasg, out);
}